// Round 13
// baseline (1334.353 us; speedup 1.0000x reference)
//
#include <hip/hip_runtime.h>

#define N_ROWS 8192
#define K_CODES 8192
#define D_DIM 512

typedef unsigned long long u64;

// ---------------------------------------------------------------------------
// Kernel 1: x_sq / e_sq, wave-parallel, bit-exact numpy pairwise emulation
// (validated R9-R12). 32 lanes per row; shfl_xor tree = numpy's add order.
// ---------------------------------------------------------------------------
__global__ __launch_bounds__(256) void vq_sq(const float* __restrict__ x,
                                             const float* __restrict__ emb,
                                             float* __restrict__ x_sq,
                                             float* __restrict__ e_sq) {
  const int t = threadIdx.x;
  const int wave = t >> 6, l = t & 63;
  const int half = l >> 5, ll = l & 31;
  const int q = ll >> 3, j = ll & 7;
  const int row = blockIdx.x * 8 + wave * 2 + half;  // 0..16383
  const float* p =
      (row < N_ROWS) ? (x + (size_t)row * D_DIM)
                     : (emb + (size_t)(row - N_ROWS) * D_DIM);
  const float v0 = p[128 * q + j];
  float r = __fmul_rn(v0, v0);
#pragma unroll
  for (int i = 1; i < 16; ++i) {
    const float v = p[128 * q + 8 * i + j];
    r = __fadd_rn(r, __fmul_rn(v, v));
  }
  r = __fadd_rn(r, __shfl_xor(r, 1, 64));
  r = __fadd_rn(r, __shfl_xor(r, 2, 64));
  r = __fadd_rn(r, __shfl_xor(r, 4, 64));
  r = __fadd_rn(r, __shfl_xor(r, 8, 64));
  r = __fadd_rn(r, __shfl_xor(r, 16, 64));
  if (ll == 0) {
    if (row < N_ROWS) x_sq[row] = r;
    else e_sq[row - N_ROWS] = r;
  }
}

// ---------------------------------------------------------------------------
// Kernel 2: distance + argmin. R12 skeleton (256 thr / 4 waves, 32n x 128k,
// 8n x 2k micro-tile, streaming XCD map, e-LDS dbuf+swizzle) + ONE change:
// x ALSO staged through async global_load_lds (xs 2 x 4 KB).
//
// Why (R12 counters): x reads compiled to SMEM s_loads (VGPR=44/SGPR=112)
// that L3/HBM-miss (~600-900cy) ON the FMA critical path, and gfx9 SMEM is
// out-of-order on lgkmcnt -> consuming them forces lgkmcnt(0), draining all
// ds_reads too. Staging x moves that latency into the vmcnt pipeline that
// already hides e's. Compute loop now touches ONLY LDS: e per-lane
// (swizzled), x wave-uniform broadcast (same-address = conflict-free).
// R11's x-staging disaster was its L2-thrashing block map (14 GB HBM), not
// the staging; R12's streaming map is kept bit-for-bit.
//
// LDS 40 KB/block -> 4 blocks/CU = 4 independent barrier groups.
// FMA chain per output bit-identical to R3-R12 (ascending dd, split@384, _rn).
// ---------------------------------------------------------------------------
__device__ __forceinline__ void compute_chunk(const float* __restrict__ esb,
                                              const float* __restrict__ xsb,
                                              int lane,
                                              float (&acc)[8][2]) {
  const int rbase = lane * 64;  // e row 2*lane
  const int lm = lane & 7;      // swizzle f(2*lane+j), j in {0,1}
#pragma unroll
  for (int g = 0; g < 8; ++g) {
    const float* p = esb + rbase + 4 * (g ^ lm);
    const float4 ev0 = *reinterpret_cast<const float4*>(p);       // row 2*lane
    const float4 ev1 = *reinterpret_cast<const float4*>(p + 32);  // row 2*lane+1
#pragma unroll
    for (int r = 0; r < 8; ++r) {
      const float4 xv =
          *reinterpret_cast<const float4*>(xsb + r * 32 + 4 * g);  // uniform
      float a0 = acc[r][0], a1 = acc[r][1];
      a0 = __fmaf_rn(xv.x, ev0.x, a0);
      a0 = __fmaf_rn(xv.y, ev0.y, a0);
      a0 = __fmaf_rn(xv.z, ev0.z, a0);
      a0 = __fmaf_rn(xv.w, ev0.w, a0);
      a1 = __fmaf_rn(xv.x, ev1.x, a1);
      a1 = __fmaf_rn(xv.y, ev1.y, a1);
      a1 = __fmaf_rn(xv.z, ev1.z, a1);
      a1 = __fmaf_rn(xv.w, ev1.w, a1);
      acc[r][0] = a0;
      acc[r][1] = a1;
    }
  }
}

// e-stage: thread t does I=0..3 16-B loads. Linear LDS dest float idx
// 4t + 1024*I; src row (t>>3)+32*I, src quad (t&7)^((t>>4)&7) (I-indep).
// x-stage: one 16-B load; dest float idx 4t; src row (t>>3), quad t&7.
// ESRC/XSRC are hoisted per-thread base pointers; advance +32 per chunk.
#define STAGE(BUF, ESRC, XSRC)                                                 \
  do {                                                                         \
    __builtin_amdgcn_global_load_lds(                                          \
        (const __attribute__((address_space(1))) void*)(ESRC),                 \
        (__attribute__((address_space(3))) void*)(&es[BUF][4 * t]), 16, 0, 0); \
    __builtin_amdgcn_global_load_lds(                                          \
        (const __attribute__((address_space(1))) void*)((ESRC) + 32 * D_DIM),  \
        (__attribute__((address_space(3))) void*)(&es[BUF][4 * t + 1024]),     \
        16, 0, 0);                                                             \
    __builtin_amdgcn_global_load_lds(                                          \
        (const __attribute__((address_space(1))) void*)((ESRC) + 64 * D_DIM),  \
        (__attribute__((address_space(3))) void*)(&es[BUF][4 * t + 2048]),     \
        16, 0, 0);                                                             \
    __builtin_amdgcn_global_load_lds(                                          \
        (const __attribute__((address_space(1))) void*)((ESRC) + 96 * D_DIM),  \
        (__attribute__((address_space(3))) void*)(&es[BUF][4 * t + 3072]),     \
        16, 0, 0);                                                             \
    __builtin_amdgcn_global_load_lds(                                          \
        (const __attribute__((address_space(1))) void*)(XSRC),                 \
        (__attribute__((address_space(3))) void*)(&xs[BUF][4 * t]), 16, 0, 0); \
  } while (0)

__global__ __launch_bounds__(256, 4) void vq_dist(
    const float* __restrict__ x, const float* __restrict__ e,
    const float* __restrict__ x_sq, const float* __restrict__ e_sq,
    u64* __restrict__ slots) {
  __shared__ float es[2][4096];  // e: 2 x 16 KB
  __shared__ float xs[2][1024];  // x: 2 x 4 KB (32 rows x 32 dd)

  const int t = threadIdx.x;
  const int lane = t & 63;
  const int w = t >> 6;

  // Streaming XCD map (R12-validated): XCD bx&7 owns 8 kb panels, sweeps
  // all 256 nb per panel. e-panel (256 KB) L2-hot; x streams per panel.
  const int bx = blockIdx.x;
  const int swz = (bx & 7) * 2048 + (bx >> 3);
  const int kb = swz >> 8;    // 0..63
  const int nb = swz & 255;   // 0..255
  const int k0 = kb * 128;
  const int n0b = nb * 32;
  const int n0w = __builtin_amdgcn_readfirstlane(n0b + w * 8);

  // Hoisted per-thread stage source bases (chunk 0); advance 32/chunk.
  const float* esrc =
      e + (size_t)(k0 + (t >> 3)) * D_DIM + 4 * ((t & 7) ^ ((t >> 4) & 7));
  const float* xsrc = x + (size_t)(n0b + (t >> 3)) * D_DIM + 4 * (t & 7);

  // Wave's x sub-block inside xs: rows w*8..w*8+7.
  const float* xsb0 = &xs[0][w * 256];
  const float* xsb1 = &xs[1][w * 256];

  float accA[8][2], accB[8][2];
#pragma unroll
  for (int r = 0; r < 8; ++r) {
    accA[r][0] = 0.0f; accA[r][1] = 0.0f;
    accB[r][0] = 0.0f; accB[r][1] = 0.0f;
  }

  // Prologue: fill buffer 0 with chunk 0.
  STAGE(0, esrc, xsrc);
  asm volatile("s_waitcnt vmcnt(0)" ::: "memory");
  __syncthreads();

  // Phase A: chunks 0..11 (dd < 384).
#pragma unroll 1
  for (int c = 0; c < 12; ++c) {
    STAGE((c + 1) & 1, esrc + (c + 1) * 32, xsrc + (c + 1) * 32);
    compute_chunk(&es[c & 1][0], (c & 1) ? xsb1 : xsb0, lane, accA);
    asm volatile("s_waitcnt vmcnt(0)" ::: "memory");
    __syncthreads();
  }
  // Phase B: chunks 12..15 (dd >= 384).
#pragma unroll 1
  for (int c = 12; c < 16; ++c) {
    if (c < 15) STAGE((c + 1) & 1, esrc + (c + 1) * 32, xsrc + (c + 1) * 32);
    compute_chunk(&es[c & 1][0], (c & 1) ? xsb1 : xsb0, lane, accB);
    asm volatile("s_waitcnt vmcnt(0)" ::: "memory");
    __syncthreads();
  }

  // Epilogue: dist = fl(fl(x_sq - 2*dot) + e_sq); packed-key argmin.
  const float4 xsqa = *reinterpret_cast<const float4*>(x_sq + n0w);
  const float4 xsqb = *reinterpret_cast<const float4*>(x_sq + n0w + 4);
  const float xsq[8] = {xsqa.x, xsqa.y, xsqa.z, xsqa.w,
                        xsqb.x, xsqb.y, xsqb.z, xsqb.w};
  const int klane = k0 + 2 * lane;
  const float2 esq = *reinterpret_cast<const float2*>(e_sq + klane);
  const float esqv[2] = {esq.x, esq.y};

#pragma unroll
  for (int r = 0; r < 8; ++r) {
    u64 best = ~0ULL;
#pragma unroll
    for (int j = 0; j < 2; ++j) {
      float dot = __fadd_rn(accA[r][j], accB[r][j]);
      float dist = __fadd_rn(__fsub_rn(xsq[r], __fmul_rn(2.0f, dot)), esqv[j]);
      unsigned int b = __float_as_uint(dist);
      unsigned int sb = (b & 0x80000000u) ? ~b : (b | 0x80000000u);
      u64 key = ((u64)sb << 32) | (unsigned)(klane + j);
      best = best < key ? best : key;
    }
#pragma unroll
    for (int off = 32; off > 0; off >>= 1) {
      u64 o = __shfl_xor((unsigned long long)best, off, 64);
      best = best < o ? best : o;
    }
    if (lane == 0) atomicMin(&slots[n0w + r], best);
  }
}

// ---------------------------------------------------------------------------
// Kernel 3: gather quantized rows (one wave per row), f32 outputs, loss
// partials into 256 hashed f64 buckets.
// ---------------------------------------------------------------------------
__global__ __launch_bounds__(256) void vq_out(
    const float* __restrict__ x, const float* __restrict__ e,
    const u64* __restrict__ slots, float* __restrict__ out_q,
    float* __restrict__ out_idx, double* __restrict__ loss_part) {
  const int t = threadIdx.x;
  const int w = t >> 6, lane = t & 63;
  const int n = blockIdx.x * 4 + w;
  const int idx = (int)(slots[n] & 0xFFFFFFFFULL);
  const float4* qr = (const float4*)(e + (size_t)idx * D_DIM);
  const float4* xr = (const float4*)(x + (size_t)n * D_DIM);
  float4* outr = (float4*)(out_q + (size_t)n * D_DIM);
  double s = 0.0;
#pragma unroll
  for (int i = 0; i < 2; ++i) {
    const int d4 = lane * 2 + i;
    float4 q = qr[d4];
    float4 xv = xr[d4];
    outr[d4] = q;
    double d0 = (double)xv.x - (double)q.x;
    double d1 = (double)xv.y - (double)q.y;
    double d2 = (double)xv.z - (double)q.z;
    double d3 = (double)xv.w - (double)q.w;
    s += d0 * d0 + d1 * d1 + d2 * d2 + d3 * d3;
  }
  for (int off = 32; off > 0; off >>= 1) s += __shfl_down(s, off, 64);
  if (lane == 0) {
    out_idx[n] = (float)idx;
    atomicAdd(&loss_part[(n * 37) & 255], s);
  }
}

__global__ void vq_loss(const double* __restrict__ loss_part,
                        float* __restrict__ out_s) {
  __shared__ double sm[256];
  const int t = threadIdx.x;
  sm[t] = loss_part[t];
  __syncthreads();
  for (int off = 128; off > 0; off >>= 1) {
    if (t < off) sm[t] += sm[t + off];
    __syncthreads();
  }
  if (t == 0) {
    double m = sm[0] / (double)(N_ROWS * D_DIM);
    out_s[0] = (float)(0.25 * m);
    out_s[1] = (float)m;
    out_s[2] = (float)(1.25 * m);
  }
}

extern "C" void kernel_launch(void* const* d_in, const int* in_sizes, int n_in,
                              void* d_out, int out_size, void* d_ws, size_t ws_size,
                              hipStream_t stream) {
  const float* x = (const float*)d_in[0];
  const float* emb = (const float*)d_in[1];
  float* out = (float*)d_out;

  // ws: [0,64K) u64 slots; [64K,96K) f32 x_sq; [96K,128K) f32 e_sq;
  //     [128K,130K) f64 loss_part[256]
  u64* slots = (u64*)d_ws;
  float* x_sq = (float*)((char*)d_ws + 65536);
  float* e_sq = (float*)((char*)d_ws + 98304);
  double* loss_part = (double*)((char*)d_ws + 131072);

  hipMemsetAsync(d_ws, 0xFF, 65536, stream);
  hipMemsetAsync(loss_part, 0, 256 * sizeof(double), stream);

  vq_sq<<<2048, 256, 0, stream>>>(x, emb, x_sq, e_sq);
  vq_dist<<<16384, 256, 0, stream>>>(x, emb, x_sq, e_sq, slots);
  vq_out<<<N_ROWS / 4, 256, 0, stream>>>(x, emb, slots, out,
                                         out + N_ROWS * D_DIM, loss_part);
  vq_loss<<<1, 256, 0, stream>>>(loss_part, out + N_ROWS * D_DIM + N_ROWS);
}

// Round 14
// 901.863 us; speedup vs baseline: 1.4796x; 1.4796x over previous
//
#include <hip/hip_runtime.h>

#define N_ROWS 8192
#define K_CODES 8192
#define D_DIM 512

typedef unsigned long long u64;

// ---------------------------------------------------------------------------
// Kernel 1: x_sq / e_sq, wave-parallel, bit-exact numpy pairwise emulation
// (validated R9-R13). 32 lanes per row; shfl_xor tree = numpy's add order.
// ---------------------------------------------------------------------------
__global__ __launch_bounds__(256) void vq_sq(const float* __restrict__ x,
                                             const float* __restrict__ emb,
                                             float* __restrict__ x_sq,
                                             float* __restrict__ e_sq) {
  const int t = threadIdx.x;
  const int wave = t >> 6, l = t & 63;
  const int half = l >> 5, ll = l & 31;
  const int q = ll >> 3, j = ll & 7;
  const int row = blockIdx.x * 8 + wave * 2 + half;  // 0..16383
  const float* p =
      (row < N_ROWS) ? (x + (size_t)row * D_DIM)
                     : (emb + (size_t)(row - N_ROWS) * D_DIM);
  const float v0 = p[128 * q + j];
  float r = __fmul_rn(v0, v0);
#pragma unroll
  for (int i = 1; i < 16; ++i) {
    const float v = p[128 * q + 8 * i + j];
    r = __fadd_rn(r, __fmul_rn(v, v));
  }
  r = __fadd_rn(r, __shfl_xor(r, 1, 64));
  r = __fadd_rn(r, __shfl_xor(r, 2, 64));
  r = __fadd_rn(r, __shfl_xor(r, 4, 64));
  r = __fadd_rn(r, __shfl_xor(r, 8, 64));
  r = __fadd_rn(r, __shfl_xor(r, 16, 64));
  if (ll == 0) {
    if (row < N_ROWS) x_sq[row] = r;
    else e_sq[row - N_ROWS] = r;
  }
}

// ---------------------------------------------------------------------------
// Kernel 2: distance + argmin. Tile 32n x 256k (256 thr, 4 waves), j=4
// micro-tile (8n x 4k), dd-chunk = 16 so e-tile stays 16 KB/buffer:
// LDS 32 KB -> 4-5 blocks/CU (R12's independent-barrier-group win kept).
//
// Why j=4 (R12 counters): x is the cold stream (1.06 GB of L2-missing
// SMEM s_loads on the FMA path, 1 per 8 FMA-instr). j=4 -> 1 per 16, and
// x passes halve (FETCH ~0.57 GB). Registers: acc 64 + ev 16 + misc ~100;
// launch_bounds(256,2) -> empirical cap 256/2=128, headroom, no spill
// (R13's failure was cap 64 < live set; R6/R9's was 8-wave blocks).
// x stays in SGPRs via wave-uniform s_load (VGPR 44 evidence, R12).
//
// LDS [256 rows][16 dd], quad-swizzle f(row)=(row>>2)&3: lane l reads rows
// 4l+j at phys quad g^(l&3). Stage: linear dest 4t+1024I (I=0..3); src row
// (t>>2)+64I, src quad (t&3)^((t>>4)&3) (I-independent).
//
// FMA chain per output bit-identical to R3-R13: chunks ascend dd (16 each),
// accA = chunks 0..23 (dd<384), accB = 24..31, _rn ops, ev.x->w order.
// ---------------------------------------------------------------------------
__device__ __forceinline__ void compute_chunk16(const float* __restrict__ esb,
                                                const float* __restrict__ xw,
                                                int dd0, int lane,
                                                float (&acc)[8][4]) {
  const int rbase = lane * 64;  // row 4*lane (16 floats/row)
  const int lm = lane & 3;      // f(4l+j) = l&3 for j<4
#pragma unroll
  for (int g = 0; g < 4; ++g) {
    const float* p = esb + rbase + 4 * (g ^ lm);
    const float4 ev0 = *reinterpret_cast<const float4*>(p);       // row 4l
    const float4 ev1 = *reinterpret_cast<const float4*>(p + 16);  // row 4l+1
    const float4 ev2 = *reinterpret_cast<const float4*>(p + 32);  // row 4l+2
    const float4 ev3 = *reinterpret_cast<const float4*>(p + 48);  // row 4l+3
#pragma unroll
    for (int r = 0; r < 8; ++r) {
      const float4 xv =
          *reinterpret_cast<const float4*>(xw + r * D_DIM + dd0 + 4 * g);
      float a0 = acc[r][0], a1 = acc[r][1], a2 = acc[r][2], a3 = acc[r][3];
      a0 = __fmaf_rn(xv.x, ev0.x, a0);
      a0 = __fmaf_rn(xv.y, ev0.y, a0);
      a0 = __fmaf_rn(xv.z, ev0.z, a0);
      a0 = __fmaf_rn(xv.w, ev0.w, a0);
      a1 = __fmaf_rn(xv.x, ev1.x, a1);
      a1 = __fmaf_rn(xv.y, ev1.y, a1);
      a1 = __fmaf_rn(xv.z, ev1.z, a1);
      a1 = __fmaf_rn(xv.w, ev1.w, a1);
      a2 = __fmaf_rn(xv.x, ev2.x, a2);
      a2 = __fmaf_rn(xv.y, ev2.y, a2);
      a2 = __fmaf_rn(xv.z, ev2.z, a2);
      a2 = __fmaf_rn(xv.w, ev2.w, a2);
      a3 = __fmaf_rn(xv.x, ev3.x, a3);
      a3 = __fmaf_rn(xv.y, ev3.y, a3);
      a3 = __fmaf_rn(xv.z, ev3.z, a3);
      a3 = __fmaf_rn(xv.w, ev3.w, a3);
      acc[r][0] = a0; acc[r][1] = a1; acc[r][2] = a2; acc[r][3] = a3;
    }
  }
}

// Stage one 16 KB chunk (256 rows x 16 dd): thread t does I=0..3 16-B loads.
// Linear dest float idx 4t + 1024I; src row (t>>2)+64I, quad (t&3)^((t>>4)&3).
#define STAGE(BUF, ESRC)                                                       \
  do {                                                                         \
    __builtin_amdgcn_global_load_lds(                                          \
        (const __attribute__((address_space(1))) void*)(ESRC),                 \
        (__attribute__((address_space(3))) void*)(&es[BUF][4 * t]), 16, 0, 0); \
    __builtin_amdgcn_global_load_lds(                                          \
        (const __attribute__((address_space(1))) void*)((ESRC) + 64 * D_DIM),  \
        (__attribute__((address_space(3))) void*)(&es[BUF][4 * t + 1024]),     \
        16, 0, 0);                                                             \
    __builtin_amdgcn_global_load_lds(                                          \
        (const __attribute__((address_space(1))) void*)((ESRC) + 128 * D_DIM), \
        (__attribute__((address_space(3))) void*)(&es[BUF][4 * t + 2048]),     \
        16, 0, 0);                                                             \
    __builtin_amdgcn_global_load_lds(                                          \
        (const __attribute__((address_space(1))) void*)((ESRC) + 192 * D_DIM), \
        (__attribute__((address_space(3))) void*)(&es[BUF][4 * t + 3072]),     \
        16, 0, 0);                                                             \
  } while (0)

__global__ __launch_bounds__(256, 2) void vq_dist(
    const float* __restrict__ x, const float* __restrict__ e,
    const float* __restrict__ x_sq, const float* __restrict__ e_sq,
    u64* __restrict__ slots) {
  __shared__ float es[2][4096];  // 2 x 16 KB

  const int t = threadIdx.x;
  const int lane = t & 63;
  const int w = t >> 6;

  // Streaming XCD map: 8192 blocks; XCD bx&7 owns 4 kb panels (256k each,
  // 512 KB L2-hot), sweeps all 256 nb per panel. x streams 32 passes.
  const int bx = blockIdx.x;
  const int swz = (bx & 7) * 1024 + (bx >> 3);
  const int kb = swz >> 8;    // 0..31
  const int nb = swz & 255;   // 0..255
  const int k0 = kb * 256;
  const int n0w = __builtin_amdgcn_readfirstlane(nb * 32 + w * 8);
  const float* xw = x + (size_t)n0w * D_DIM;

  // Hoisted per-thread stage source base (chunk 0); advance 16 floats/chunk.
  const float* esrc =
      e + (size_t)(k0 + (t >> 2)) * D_DIM + 4 * ((t & 3) ^ ((t >> 4) & 3));

  float accA[8][4], accB[8][4];
#pragma unroll
  for (int r = 0; r < 8; ++r)
#pragma unroll
    for (int j = 0; j < 4; ++j) { accA[r][j] = 0.0f; accB[r][j] = 0.0f; }

  // Prologue: fill buffer 0 with chunk 0.
  STAGE(0, esrc);
  asm volatile("s_waitcnt vmcnt(0)" ::: "memory");
  __syncthreads();

  // Phase A: chunks 0..23 (dd < 384).
#pragma unroll 1
  for (int c = 0; c < 24; ++c) {
    STAGE((c + 1) & 1, esrc + (c + 1) * 16);
    compute_chunk16(&es[c & 1][0], xw, c * 16, lane, accA);
    asm volatile("s_waitcnt vmcnt(0)" ::: "memory");
    __syncthreads();
  }
  // Phase B: chunks 24..31 (dd >= 384).
#pragma unroll 1
  for (int c = 24; c < 32; ++c) {
    if (c < 31) STAGE((c + 1) & 1, esrc + (c + 1) * 16);
    compute_chunk16(&es[c & 1][0], xw, c * 16, lane, accB);
    asm volatile("s_waitcnt vmcnt(0)" ::: "memory");
    __syncthreads();
  }

  // Epilogue: dist = fl(fl(x_sq - 2*dot) + e_sq); packed-key argmin.
  const float4 xsqa = *reinterpret_cast<const float4*>(x_sq + n0w);
  const float4 xsqb = *reinterpret_cast<const float4*>(x_sq + n0w + 4);
  const float xsq[8] = {xsqa.x, xsqa.y, xsqa.z, xsqa.w,
                        xsqb.x, xsqb.y, xsqb.z, xsqb.w};
  const int klane = k0 + 4 * lane;
  const float4 esq = *reinterpret_cast<const float4*>(e_sq + klane);
  const float esqv[4] = {esq.x, esq.y, esq.z, esq.w};

#pragma unroll
  for (int r = 0; r < 8; ++r) {
    u64 best = ~0ULL;
#pragma unroll
    for (int j = 0; j < 4; ++j) {
      float dot = __fadd_rn(accA[r][j], accB[r][j]);
      float dist = __fadd_rn(__fsub_rn(xsq[r], __fmul_rn(2.0f, dot)), esqv[j]);
      unsigned int b = __float_as_uint(dist);
      unsigned int sb = (b & 0x80000000u) ? ~b : (b | 0x80000000u);
      u64 key = ((u64)sb << 32) | (unsigned)(klane + j);
      best = best < key ? best : key;
    }
#pragma unroll
    for (int off = 32; off > 0; off >>= 1) {
      u64 o = __shfl_xor((unsigned long long)best, off, 64);
      best = best < o ? best : o;
    }
    if (lane == 0) atomicMin(&slots[n0w + r], best);
  }
}

// ---------------------------------------------------------------------------
// Kernel 3: gather quantized rows (one wave per row), f32 outputs, loss
// partials into 256 hashed f64 buckets.
// ---------------------------------------------------------------------------
__global__ __launch_bounds__(256) void vq_out(
    const float* __restrict__ x, const float* __restrict__ e,
    const u64* __restrict__ slots, float* __restrict__ out_q,
    float* __restrict__ out_idx, double* __restrict__ loss_part) {
  const int t = threadIdx.x;
  const int w = t >> 6, lane = t & 63;
  const int n = blockIdx.x * 4 + w;
  const int idx = (int)(slots[n] & 0xFFFFFFFFULL);
  const float4* qr = (const float4*)(e + (size_t)idx * D_DIM);
  const float4* xr = (const float4*)(x + (size_t)n * D_DIM);
  float4* outr = (float4*)(out_q + (size_t)n * D_DIM);
  double s = 0.0;
#pragma unroll
  for (int i = 0; i < 2; ++i) {
    const int d4 = lane * 2 + i;
    float4 q = qr[d4];
    float4 xv = xr[d4];
    outr[d4] = q;
    double d0 = (double)xv.x - (double)q.x;
    double d1 = (double)xv.y - (double)q.y;
    double d2 = (double)xv.z - (double)q.z;
    double d3 = (double)xv.w - (double)q.w;
    s += d0 * d0 + d1 * d1 + d2 * d2 + d3 * d3;
  }
  for (int off = 32; off > 0; off >>= 1) s += __shfl_down(s, off, 64);
  if (lane == 0) {
    out_idx[n] = (float)idx;
    atomicAdd(&loss_part[(n * 37) & 255], s);
  }
}

__global__ void vq_loss(const double* __restrict__ loss_part,
                        float* __restrict__ out_s) {
  __shared__ double sm[256];
  const int t = threadIdx.x;
  sm[t] = loss_part[t];
  __syncthreads();
  for (int off = 128; off > 0; off >>= 1) {
    if (t < off) sm[t] += sm[t + off];
    __syncthreads();
  }
  if (t == 0) {
    double m = sm[0] / (double)(N_ROWS * D_DIM);
    out_s[0] = (float)(0.25 * m);
    out_s[1] = (float)m;
    out_s[2] = (float)(1.25 * m);
  }
}

extern "C" void kernel_launch(void* const* d_in, const int* in_sizes, int n_in,
                              void* d_out, int out_size, void* d_ws, size_t ws_size,
                              hipStream_t stream) {
  const float* x = (const float*)d_in[0];
  const float* emb = (const float*)d_in[1];
  float* out = (float*)d_out;

  // ws: [0,64K) u64 slots; [64K,96K) f32 x_sq; [96K,128K) f32 e_sq;
  //     [128K,130K) f64 loss_part[256]
  u64* slots = (u64*)d_ws;
  float* x_sq = (float*)((char*)d_ws + 65536);
  float* e_sq = (float*)((char*)d_ws + 98304);
  double* loss_part = (double*)((char*)d_ws + 131072);

  hipMemsetAsync(d_ws, 0xFF, 65536, stream);
  hipMemsetAsync(loss_part, 0, 256 * sizeof(double), stream);

  vq_sq<<<2048, 256, 0, stream>>>(x, emb, x_sq, e_sq);
  vq_dist<<<8192, 256, 0, stream>>>(x, emb, x_sq, e_sq, slots);
  vq_out<<<N_ROWS / 4, 256, 0, stream>>>(x, emb, slots, out,
                                         out + N_ROWS * D_DIM, loss_part);
  vq_loss<<<1, 256, 0, stream>>>(loss_part, out + N_ROWS * D_DIM + N_ROWS);
}

// Round 15
// 874.816 us; speedup vs baseline: 1.5253x; 1.0309x over previous
//
#include <hip/hip_runtime.h>

#define N_ROWS 8192
#define K_CODES 8192
#define D_DIM 512

typedef unsigned long long u64;

// ---------------------------------------------------------------------------
// Kernel 1: x_sq / e_sq, wave-parallel, bit-exact numpy pairwise emulation
// (validated R9-R14). 32 lanes per row; shfl_xor tree = numpy's add order.
// ---------------------------------------------------------------------------
__global__ __launch_bounds__(256) void vq_sq(const float* __restrict__ x,
                                             const float* __restrict__ emb,
                                             float* __restrict__ x_sq,
                                             float* __restrict__ e_sq) {
  const int t = threadIdx.x;
  const int wave = t >> 6, l = t & 63;
  const int half = l >> 5, ll = l & 31;
  const int q = ll >> 3, j = ll & 7;
  const int row = blockIdx.x * 8 + wave * 2 + half;  // 0..16383
  const float* p =
      (row < N_ROWS) ? (x + (size_t)row * D_DIM)
                     : (emb + (size_t)(row - N_ROWS) * D_DIM);
  const float v0 = p[128 * q + j];
  float r = __fmul_rn(v0, v0);
#pragma unroll
  for (int i = 1; i < 16; ++i) {
    const float v = p[128 * q + 8 * i + j];
    r = __fadd_rn(r, __fmul_rn(v, v));
  }
  r = __fadd_rn(r, __shfl_xor(r, 1, 64));
  r = __fadd_rn(r, __shfl_xor(r, 2, 64));
  r = __fadd_rn(r, __shfl_xor(r, 4, 64));
  r = __fadd_rn(r, __shfl_xor(r, 8, 64));
  r = __fadd_rn(r, __shfl_xor(r, 16, 64));
  if (ll == 0) {
    if (row < N_ROWS) x_sq[row] = r;
    else e_sq[row - N_ROWS] = r;
  }
}

// ---------------------------------------------------------------------------
// Kernel 2: distance + argmin. R14 skeleton (32n x 256k, 256 thr, j=4,
// dd-chunk 16, LDS 2 x 16 KB, streaming XCD map) + ONE change:
// SCATTERED k-row ownership to kill the 16-way LDS bank conflict.
//
// R14 arithmetic: 16-float rows put lane base l*64B = 0 mod 128B -> bank
// determined only by 2-bit quad -> 16 lanes per 4-bank group -> 16 clk per
// b128 (structural min 8). LDS pipe hit 437us = co-critical with FMA pipe.
// Fix: lane l owns rows {l, l+64, l+128, l+192}. Read addr = l*16 floats +
// 4*(g ^ ((l>>1)&3)) -> bank = 4*(l&7) + quad = full 32-bank spread,
// 8 lanes/group = 8 clk = optimal. Layout P(r,q) = r*16 + 4*(q^((r>>1)&3)).
// Stage: linear dest 4t+1024I; src row (t>>2)+64I, quad (t&3)^((t>>3)&3).
//
// FMA chain per output bit-identical to R3-R14: chunks ascend dd (16 each),
// accA = chunks 0..23 (dd<384), accB = 24..31, _rn ops, ev.x->w order.
// ---------------------------------------------------------------------------
__device__ __forceinline__ void compute_chunk16(const float* __restrict__ esb,
                                                const float* __restrict__ xw,
                                                int dd0, int lane,
                                                float (&acc)[8][4]) {
  const int lbase = lane * 16;       // row l (16 floats/row)
  const int lm = (lane >> 1) & 3;    // swizzle hash, j-independent
#pragma unroll
  for (int g = 0; g < 4; ++g) {
    const float* p = esb + lbase + 4 * (g ^ lm);
    const float4 ev0 = *reinterpret_cast<const float4*>(p);         // row l
    const float4 ev1 = *reinterpret_cast<const float4*>(p + 1024);  // row l+64
    const float4 ev2 = *reinterpret_cast<const float4*>(p + 2048);  // row l+128
    const float4 ev3 = *reinterpret_cast<const float4*>(p + 3072);  // row l+192
#pragma unroll
    for (int r = 0; r < 8; ++r) {
      const float4 xv =
          *reinterpret_cast<const float4*>(xw + r * D_DIM + dd0 + 4 * g);
      float a0 = acc[r][0], a1 = acc[r][1], a2 = acc[r][2], a3 = acc[r][3];
      a0 = __fmaf_rn(xv.x, ev0.x, a0);
      a0 = __fmaf_rn(xv.y, ev0.y, a0);
      a0 = __fmaf_rn(xv.z, ev0.z, a0);
      a0 = __fmaf_rn(xv.w, ev0.w, a0);
      a1 = __fmaf_rn(xv.x, ev1.x, a1);
      a1 = __fmaf_rn(xv.y, ev1.y, a1);
      a1 = __fmaf_rn(xv.z, ev1.z, a1);
      a1 = __fmaf_rn(xv.w, ev1.w, a1);
      a2 = __fmaf_rn(xv.x, ev2.x, a2);
      a2 = __fmaf_rn(xv.y, ev2.y, a2);
      a2 = __fmaf_rn(xv.z, ev2.z, a2);
      a2 = __fmaf_rn(xv.w, ev2.w, a2);
      a3 = __fmaf_rn(xv.x, ev3.x, a3);
      a3 = __fmaf_rn(xv.y, ev3.y, a3);
      a3 = __fmaf_rn(xv.z, ev3.z, a3);
      a3 = __fmaf_rn(xv.w, ev3.w, a3);
      acc[r][0] = a0; acc[r][1] = a1; acc[r][2] = a2; acc[r][3] = a3;
    }
  }
}

// Stage one 16 KB chunk (256 rows x 16 dd): thread t does I=0..3 16-B loads.
// Dest float idx 4t + 1024I -> row (t>>2)+64I, phys quad t&3; source logical
// quad = (t&3) ^ (((t>>2)+64I)>>1 & 3) = (t&3)^((t>>3)&3)  (I-independent).
#define STAGE(BUF, ESRC)                                                       \
  do {                                                                         \
    __builtin_amdgcn_global_load_lds(                                          \
        (const __attribute__((address_space(1))) void*)(ESRC),                 \
        (__attribute__((address_space(3))) void*)(&es[BUF][4 * t]), 16, 0, 0); \
    __builtin_amdgcn_global_load_lds(                                          \
        (const __attribute__((address_space(1))) void*)((ESRC) + 64 * D_DIM),  \
        (__attribute__((address_space(3))) void*)(&es[BUF][4 * t + 1024]),     \
        16, 0, 0);                                                             \
    __builtin_amdgcn_global_load_lds(                                          \
        (const __attribute__((address_space(1))) void*)((ESRC) + 128 * D_DIM), \
        (__attribute__((address_space(3))) void*)(&es[BUF][4 * t + 2048]),     \
        16, 0, 0);                                                             \
    __builtin_amdgcn_global_load_lds(                                          \
        (const __attribute__((address_space(1))) void*)((ESRC) + 192 * D_DIM), \
        (__attribute__((address_space(3))) void*)(&es[BUF][4 * t + 3072]),     \
        16, 0, 0);                                                             \
  } while (0)

__global__ __launch_bounds__(256, 2) void vq_dist(
    const float* __restrict__ x, const float* __restrict__ e,
    const float* __restrict__ x_sq, const float* __restrict__ e_sq,
    u64* __restrict__ slots) {
  __shared__ float es[2][4096];  // 2 x 16 KB

  const int t = threadIdx.x;
  const int lane = t & 63;
  const int w = t >> 6;

  // Streaming XCD map (R12/R14-validated): XCD bx&7 owns 4 kb panels
  // (256k x 512d = 512 KB L2-hot), sweeps all 256 nb per panel.
  const int bx = blockIdx.x;
  const int swz = (bx & 7) * 1024 + (bx >> 3);
  const int kb = swz >> 8;    // 0..31
  const int nb = swz & 255;   // 0..255
  const int k0 = kb * 256;
  const int n0w = __builtin_amdgcn_readfirstlane(nb * 32 + w * 8);
  const float* xw = x + (size_t)n0w * D_DIM;

  // Hoisted per-thread stage source base (chunk 0); advance 16 floats/chunk.
  const float* esrc =
      e + (size_t)(k0 + (t >> 2)) * D_DIM + 4 * ((t & 3) ^ ((t >> 3) & 3));

  float accA[8][4], accB[8][4];
#pragma unroll
  for (int r = 0; r < 8; ++r)
#pragma unroll
    for (int j = 0; j < 4; ++j) { accA[r][j] = 0.0f; accB[r][j] = 0.0f; }

  // Prologue: fill buffer 0 with chunk 0.
  STAGE(0, esrc);
  asm volatile("s_waitcnt vmcnt(0)" ::: "memory");
  __syncthreads();

  // Phase A: chunks 0..23 (dd < 384).
#pragma unroll 1
  for (int c = 0; c < 24; ++c) {
    STAGE((c + 1) & 1, esrc + (c + 1) * 16);
    compute_chunk16(&es[c & 1][0], xw, c * 16, lane, accA);
    asm volatile("s_waitcnt vmcnt(0)" ::: "memory");
    __syncthreads();
  }
  // Phase B: chunks 24..31 (dd >= 384).
#pragma unroll 1
  for (int c = 24; c < 32; ++c) {
    if (c < 31) STAGE((c + 1) & 1, esrc + (c + 1) * 16);
    compute_chunk16(&es[c & 1][0], xw, c * 16, lane, accB);
    asm volatile("s_waitcnt vmcnt(0)" ::: "memory");
    __syncthreads();
  }

  // Epilogue: dist = fl(fl(x_sq - 2*dot) + e_sq); packed-key argmin.
  // Lane owns k = k0 + lane + 64*j (scattered ownership).
  const float4 xsqa = *reinterpret_cast<const float4*>(x_sq + n0w);
  const float4 xsqb = *reinterpret_cast<const float4*>(x_sq + n0w + 4);
  const float xsq[8] = {xsqa.x, xsqa.y, xsqa.z, xsqa.w,
                        xsqb.x, xsqb.y, xsqb.z, xsqb.w};
  const int klane = k0 + lane;
  const float esqv[4] = {e_sq[klane], e_sq[klane + 64], e_sq[klane + 128],
                         e_sq[klane + 192]};

#pragma unroll
  for (int r = 0; r < 8; ++r) {
    u64 best = ~0ULL;
#pragma unroll
    for (int j = 0; j < 4; ++j) {
      float dot = __fadd_rn(accA[r][j], accB[r][j]);
      float dist = __fadd_rn(__fsub_rn(xsq[r], __fmul_rn(2.0f, dot)), esqv[j]);
      unsigned int b = __float_as_uint(dist);
      unsigned int sb = (b & 0x80000000u) ? ~b : (b | 0x80000000u);
      u64 key = ((u64)sb << 32) | (unsigned)(klane + 64 * j);
      best = best < key ? best : key;
    }
#pragma unroll
    for (int off = 32; off > 0; off >>= 1) {
      u64 o = __shfl_xor((unsigned long long)best, off, 64);
      best = best < o ? best : o;
    }
    if (lane == 0) atomicMin(&slots[n0w + r], best);
  }
}

// ---------------------------------------------------------------------------
// Kernel 3: gather quantized rows (one wave per row), f32 outputs, loss
// partials into 256 hashed f64 buckets.
// ---------------------------------------------------------------------------
__global__ __launch_bounds__(256) void vq_out(
    const float* __restrict__ x, const float* __restrict__ e,
    const u64* __restrict__ slots, float* __restrict__ out_q,
    float* __restrict__ out_idx, double* __restrict__ loss_part) {
  const int t = threadIdx.x;
  const int w = t >> 6, lane = t & 63;
  const int n = blockIdx.x * 4 + w;
  const int idx = (int)(slots[n] & 0xFFFFFFFFULL);
  const float4* qr = (const float4*)(e + (size_t)idx * D_DIM);
  const float4* xr = (const float4*)(x + (size_t)n * D_DIM);
  float4* outr = (float4*)(out_q + (size_t)n * D_DIM);
  double s = 0.0;
#pragma unroll
  for (int i = 0; i < 2; ++i) {
    const int d4 = lane * 2 + i;
    float4 q = qr[d4];
    float4 xv = xr[d4];
    outr[d4] = q;
    double d0 = (double)xv.x - (double)q.x;
    double d1 = (double)xv.y - (double)q.y;
    double d2 = (double)xv.z - (double)q.z;
    double d3 = (double)xv.w - (double)q.w;
    s += d0 * d0 + d1 * d1 + d2 * d2 + d3 * d3;
  }
  for (int off = 32; off > 0; off >>= 1) s += __shfl_down(s, off, 64);
  if (lane == 0) {
    out_idx[n] = (float)idx;
    atomicAdd(&loss_part[(n * 37) & 255], s);
  }
}

__global__ void vq_loss(const double* __restrict__ loss_part,
                        float* __restrict__ out_s) {
  __shared__ double sm[256];
  const int t = threadIdx.x;
  sm[t] = loss_part[t];
  __syncthreads();
  for (int off = 128; off > 0; off >>= 1) {
    if (t < off) sm[t] += sm[t + off];
    __syncthreads();
  }
  if (t == 0) {
    double m = sm[0] / (double)(N_ROWS * D_DIM);
    out_s[0] = (float)(0.25 * m);
    out_s[1] = (float)m;
    out_s[2] = (float)(1.25 * m);
  }
}

extern "C" void kernel_launch(void* const* d_in, const int* in_sizes, int n_in,
                              void* d_out, int out_size, void* d_ws, size_t ws_size,
                              hipStream_t stream) {
  const float* x = (const float*)d_in[0];
  const float* emb = (const float*)d_in[1];
  float* out = (float*)d_out;

  // ws: [0,64K) u64 slots; [64K,96K) f32 x_sq; [96K,128K) f32 e_sq;
  //     [128K,130K) f64 loss_part[256]
  u64* slots = (u64*)d_ws;
  float* x_sq = (float*)((char*)d_ws + 65536);
  float* e_sq = (float*)((char*)d_ws + 98304);
  double* loss_part = (double*)((char*)d_ws + 131072);

  hipMemsetAsync(d_ws, 0xFF, 65536, stream);
  hipMemsetAsync(loss_part, 0, 256 * sizeof(double), stream);

  vq_sq<<<2048, 256, 0, stream>>>(x, emb, x_sq, e_sq);
  vq_dist<<<8192, 256, 0, stream>>>(x, emb, x_sq, e_sq, slots);
  vq_out<<<N_ROWS / 4, 256, 0, stream>>>(x, emb, slots, out,
                                         out + N_ROWS * D_DIM, loss_part);
  vq_loss<<<1, 256, 0, stream>>>(loss_part, out + N_ROWS * D_DIM + N_ROWS);
}